// Round 1
// baseline (796.326 us; speedup 1.0000x reference)
//
#include <hip/hip_runtime.h>
#include <stdint.h>

#define IN_F 256
#define OUT_F 128
#define NCOLS 896   // 768 node-msg cols + 128 self cols
#define BM 64
#define BN 128
#define BK 32

using bf16x8 = __attribute__((ext_vector_type(8))) __bf16;
using f32x4  = __attribute__((ext_vector_type(4))) float;

static __device__ __forceinline__ unsigned short f2bf(float f) {
    unsigned u = __float_as_uint(f);
    u = u + 0x7fffu + ((u >> 16) & 1u);   // RNE
    return (unsigned short)(u >> 16);
}

static __device__ __forceinline__ void async_load16(const void* g, void* l) {
    __builtin_amdgcn_global_load_lds(
        (__attribute__((address_space(1))) void*)g,
        (__attribute__((address_space(3))) void*)l,
        16, 0, 0);
}

// ---- h (f32) -> bf16 ----
__global__ void k_conv_h(const float* __restrict__ h, unsigned short* __restrict__ hb, int total8) {
    int i = blockIdx.x * blockDim.x + threadIdx.x;
    if (i >= total8) return;
    const float4* src = ((const float4*)h) + (size_t)i * 2;
    float4 a = src[0], b = src[1];
    union { unsigned short us[8]; uint4 v; } u;
    u.us[0] = f2bf(a.x); u.us[1] = f2bf(a.y); u.us[2] = f2bf(a.z); u.us[3] = f2bf(a.w);
    u.us[4] = f2bf(b.x); u.us[5] = f2bf(b.y); u.us[6] = f2bf(b.z); u.us[7] = f2bf(b.w);
    ((uint4*)hb)[i] = u.v;
}

// ---- build Wt[896][256] = [W_node | W_self]^T in bf16 ----
__global__ void k_conv_w(const float* __restrict__ Wn, const float* __restrict__ Ws,
                         unsigned short* __restrict__ Wt, int total) {
    int i = blockIdx.x * blockDim.x + threadIdx.x;  // i = k*896 + c  (c fastest -> coalesced reads)
    if (i >= total) return;
    int k = i / NCOLS, c = i - k * NCOLS;
    float v = (c < 768) ? Wn[(size_t)k * 768 + c] : Ws[(size_t)k * 128 + (c - 768)];
    Wt[(size_t)c * IN_F + k] = f2bf(v);
}

// ---- GEMM: P[N,896] = bf16( (h @ [W_node|W_self] + bias) * (norm | 1) ) ----
__global__ void __launch_bounds__(256) k_gemm(
    const unsigned short* __restrict__ hb,   // [N,256] bf16
    const unsigned short* __restrict__ Wt,   // [896,256] bf16 (transposed weights)
    const float* __restrict__ b_node, const float* __restrict__ b_self,
    const float* __restrict__ norm,
    unsigned short* __restrict__ P, int N)
{
    __shared__ char lds[(BM + BN) * BK * 2];   // A: 4096 B, B: 8192 B
    char* Ab = lds;
    char* Bb = lds + BM * BK * 2;

    const int tid = threadIdx.x;
    const int wid = tid >> 6, lane = tid & 63;
    const int lrow = lane & 15, s = lane >> 4;
    const int wr = wid >> 1, wc = wid & 1;
    const int r0 = blockIdx.x * BM;
    const int c0 = blockIdx.y * BN;

    // --- staging sources (XOR swizzle applied on global side; LDS dest linear) ---
    const int arow = tid >> 2;
    const int achunk = (tid & 3) ^ ((arow >> 1) & 3);
    int agrow = r0 + arow; if (agrow >= N) agrow = N - 1;   // clamp: garbage rows never stored
    const unsigned short* aseg = hb + (size_t)agrow * IN_F + achunk * 8;

    const int bcol0 = tid >> 2;
    const int bchunk0 = (tid & 3) ^ ((bcol0 >> 1) & 3);
    const unsigned short* bseg0 = Wt + (size_t)(c0 + bcol0) * IN_F + bchunk0 * 8;
    const int idx1 = tid + 256;
    const int bcol1 = idx1 >> 2;
    const int bchunk1 = (idx1 & 3) ^ ((bcol1 >> 1) & 3);
    const unsigned short* bseg1 = Wt + (size_t)(c0 + bcol1) * IN_F + bchunk1 * 8;

    // --- fragment LDS byte offsets (match the swizzle) ---
    int a_off[2], b_off[4];
#pragma unroll
    for (int m = 0; m < 2; ++m) {
        int rl = wr * 32 + m * 16 + lrow;
        a_off[m] = rl * 64 + ((s ^ ((rl >> 1) & 3)) << 4);
    }
#pragma unroll
    for (int n = 0; n < 4; ++n) {
        int cl = wc * 64 + n * 16 + lrow;
        b_off[n] = cl * 64 + ((s ^ ((cl >> 1) & 3)) << 4);
    }

    f32x4 acc[2][4] = {};

    for (int kk = 0; kk < IN_F / BK; ++kk) {
        async_load16(aseg + kk * BK, Ab + tid * 16);
        async_load16(bseg0 + kk * BK, Bb + tid * 16);
        async_load16(bseg1 + kk * BK, Bb + (tid + 256) * 16);
        __syncthreads();   // compiler drains vmcnt before s_barrier

        bf16x8 af[2], bfv[4];
#pragma unroll
        for (int m = 0; m < 2; ++m) af[m] = *(const bf16x8*)(Ab + a_off[m]);
#pragma unroll
        for (int n = 0; n < 4; ++n) bfv[n] = *(const bf16x8*)(Bb + b_off[n]);
#pragma unroll
        for (int m = 0; m < 2; ++m)
#pragma unroll
            for (int n = 0; n < 4; ++n)
                acc[m][n] = __builtin_amdgcn_mfma_f32_16x16x32_bf16(af[m], bfv[n], acc[m][n], 0, 0, 0);
        __syncthreads();
    }

    // --- epilogue: +bias, src-side norm pre-scale (node cols only), bf16 store ---
    const bool isSelf = (c0 >= 768);   // blockIdx.y == 6 -> W_self columns
#pragma unroll
    for (int m = 0; m < 2; ++m) {
        const int rbase = r0 + wr * 32 + m * 16 + s * 4;
#pragma unroll
        for (int n = 0; n < 4; ++n) {
            const int cg = c0 + wc * 64 + n * 16 + lrow;
            const float bv = isSelf ? b_self[cg - 768] : b_node[cg];
#pragma unroll
            for (int r = 0; r < 4; ++r) {
                const int rg = rbase + r;
                if (rg < N) {
                    float v = acc[m][n][r] + bv;
                    if (!isSelf) v *= norm[rg];
                    P[(size_t)rg * NCOLS + cg] = f2bf(v);
                }
            }
        }
    }
}

// ---- edge kernel: one wave per edge, lane owns cols {2l, 2l+1} ----
__global__ void __launch_bounds__(256) k_edge(
    const unsigned short* __restrict__ P, float* __restrict__ accum,
    const float* __restrict__ degrees, const float* __restrict__ norm,
    const int* __restrict__ src, const int* __restrict__ dst,
    const float* __restrict__ W_edge, int E)
{
    int e = blockIdx.x * 4 + (threadIdx.x >> 6);
    if (e >= E) return;
    const int lane = threadIdx.x & 63;
    const int c = lane * 2;

    const int sN = src[e];
    const int dN = dst[e];
    const float nrm = norm[sN];

    float dg[6];
#pragma unroll
    for (int i = 0; i < 6; ++i) dg[i] = degrees[(size_t)e * 6 + i];

    float m0 = 0.f, m1 = 0.f;
#pragma unroll
    for (int i = 0; i < 6; ++i) {
        float2 w = *(const float2*)(W_edge + i * OUT_F + c);
        m0 += dg[i] * w.x;
        m1 += dg[i] * w.y;
    }
    m0 *= nrm; m1 *= nrm;

    const unsigned* Ps = (const unsigned*)(P + (size_t)sN * NCOLS);
#pragma unroll
    for (int i = 0; i < 6; ++i) {
        if (dg[i] > 0.f) {                       // wave-uniform branch
            unsigned u = Ps[(i * OUT_F + c) >> 1];
            m0 += __uint_as_float(u << 16);
            m1 += __uint_as_float(u & 0xffff0000u);
        }
    }

    float* ap = accum + (size_t)dN * OUT_F + c;
    __hip_atomic_fetch_add(ap,     m0, __ATOMIC_RELAXED, __HIP_MEMORY_SCOPE_AGENT);
    __hip_atomic_fetch_add(ap + 1, m1, __ATOMIC_RELAXED, __HIP_MEMORY_SCOPE_AGENT);
}

// ---- epilogue: out = relu(accum*norm + h_self + bias) ----
__global__ void k_epi(const float* __restrict__ accum, const unsigned short* __restrict__ P,
                      const float* __restrict__ norm, const float* __restrict__ bias,
                      float* __restrict__ out, int N)
{
    int i = blockIdx.x * blockDim.x + threadIdx.x;   // over N*32 float4s
    if (i >= N * (OUT_F / 4)) return;
    int row = i >> 5, cp = i & 31, cc = cp * 4;
    float4 a = ((const float4*)accum)[i];
    float nrm = norm[row];
    uint2 u = *(const uint2*)(P + (size_t)row * NCOLS + 768 + cc);
    float s0 = __uint_as_float(u.x << 16);
    float s1 = __uint_as_float(u.x & 0xffff0000u);
    float s2 = __uint_as_float(u.y << 16);
    float s3 = __uint_as_float(u.y & 0xffff0000u);
    float4 b = ((const float4*)bias)[cp];
    float4 o;
    o.x = fmaxf(a.x * nrm + s0 + b.x, 0.f);
    o.y = fmaxf(a.y * nrm + s1 + b.y, 0.f);
    o.z = fmaxf(a.z * nrm + s2 + b.z, 0.f);
    o.w = fmaxf(a.w * nrm + s3 + b.w, 0.f);
    ((float4*)out)[i] = o;
}

extern "C" void kernel_launch(void* const* d_in, const int* in_sizes, int n_in,
                              void* d_out, int out_size, void* d_ws, size_t ws_size,
                              hipStream_t stream)
{
    const float* h       = (const float*)d_in[0];
    const float* degrees = (const float*)d_in[1];
    const float* norm    = (const float*)d_in[2];
    const int*   src     = (const int*)d_in[3];
    const int*   dst     = (const int*)d_in[4];
    const float* W_self  = (const float*)d_in[5];  (void)W_self;
    const float* b_self  = (const float*)d_in[6];
    const float* W_node  = (const float*)d_in[7];
    const float* b_node  = (const float*)d_in[8];
    const float* W_edge  = (const float*)d_in[9];
    const float* bias    = (const float*)d_in[10];
    float* out = (float*)d_out;

    const int N = in_sizes[2];   // norm is [N,1]
    const int E = in_sizes[3];   // src is [E]

    // workspace layout (~141.3 MB total)
    char* ws = (char*)d_ws;
    size_t szP   = (size_t)N * NCOLS * 2;                 // 89.6 MB  bf16 P
    size_t offAcc = (szP + 255) & ~(size_t)255;
    size_t szAcc = (size_t)N * OUT_F * 4;                 // 25.6 MB  f32 accum
    size_t offHb = (offAcc + szAcc + 255) & ~(size_t)255;
    size_t szHb  = (size_t)N * IN_F * 2;                  // 25.6 MB  bf16 h
    size_t offWt = (offHb + szHb + 255) & ~(size_t)255;   // + 448 KB bf16 Wt

    unsigned short* P     = (unsigned short*)(ws);
    float*          accum = (float*)(ws + offAcc);
    unsigned short* hb    = (unsigned short*)(ws + offHb);
    unsigned short* Wt    = (unsigned short*)(ws + offWt);

    hipMemsetAsync(accum, 0, szAcc, stream);

    int t8 = N * (IN_F / 8);
    k_conv_h<<<(t8 + 255) / 256, 256, 0, stream>>>(h, hb, t8);

    int tw = IN_F * NCOLS;
    k_conv_w<<<(tw + 255) / 256, 256, 0, stream>>>(W_node, W_self, Wt, tw);

    dim3 gg((N + BM - 1) / BM, NCOLS / BN);
    k_gemm<<<gg, 256, 0, stream>>>(hb, Wt, b_node, b_self, norm, P, N);

    k_edge<<<(E + 3) / 4, 256, 0, stream>>>(P, accum, degrees, norm, src, dst, W_edge, E);

    int t4 = N * (OUT_F / 4);
    k_epi<<<(t4 + 255) / 256, 256, 0, stream>>>(accum, P, norm, bias, out, N);
}

// Round 2
// 399.254 us; speedup vs baseline: 1.9945x; 1.9945x over previous
//
#include <hip/hip_runtime.h>
#include <stdint.h>

#define IN_F 256
#define OUT_F 128
#define NCOLS 1024   // 768 node-msg cols + 128 sum-slice + 128 self
#define BM 64
#define BN 128
#define BK 32

using bf16x8 = __attribute__((ext_vector_type(8))) __bf16;
using f32x4  = __attribute__((ext_vector_type(4))) float;

static __device__ __forceinline__ unsigned short f2bf(float f) {
    unsigned u = __float_as_uint(f);
    u = u + 0x7fffu + ((u >> 16) & 1u);   // RNE
    return (unsigned short)(u >> 16);
}
static __device__ __forceinline__ float bf_lo(unsigned u) { return __uint_as_float(u << 16); }
static __device__ __forceinline__ float bf_hi(unsigned u) { return __uint_as_float(u & 0xffff0000u); }

static __device__ __forceinline__ void async_load16(const void* g, void* l) {
    __builtin_amdgcn_global_load_lds(
        (__attribute__((address_space(1))) void*)g,
        (__attribute__((address_space(3))) void*)l,
        16, 0, 0);
}

// ---- h (f32) -> bf16 ----
__global__ void k_conv_h(const float* __restrict__ h, unsigned short* __restrict__ hb, int total8) {
    int i = blockIdx.x * blockDim.x + threadIdx.x;
    if (i >= total8) return;
    const float4* src = ((const float4*)h) + (size_t)i * 2;
    float4 a = src[0], b = src[1];
    union { unsigned short us[8]; uint4 v; } u;
    u.us[0] = f2bf(a.x); u.us[1] = f2bf(a.y); u.us[2] = f2bf(a.z); u.us[3] = f2bf(a.w);
    u.us[4] = f2bf(b.x); u.us[5] = f2bf(b.y); u.us[6] = f2bf(b.z); u.us[7] = f2bf(b.w);
    ((uint4*)hb)[i] = u.v;
}

// ---- Wt[1024][256] = [W_node | sum(W_node slices) | W_self]^T, bf16 ----
__global__ void k_conv_w(const float* __restrict__ Wn, const float* __restrict__ Ws,
                         unsigned short* __restrict__ Wt, int total) {
    int i = blockIdx.x * blockDim.x + threadIdx.x;   // i = k*1024 + c
    if (i >= total) return;
    int k = i >> 10, c = i & 1023;
    float v;
    if (c < 768) {
        v = Wn[(size_t)k * 768 + c];
    } else if (c < 896) {
        int j = c - 768; v = 0.f;
#pragma unroll
        for (int s = 0; s < 6; ++s) v += Wn[(size_t)k * 768 + s * 128 + j];
    } else {
        v = Ws[(size_t)k * 128 + (c - 896)];
    }
    Wt[(size_t)c * IN_F + k] = f2bf(v);
}

// ---- combined bias vector bvec[1024] ----
__global__ void k_conv_b(const float* __restrict__ bn, const float* __restrict__ bs,
                         float* __restrict__ bvec) {
    int c = blockIdx.x * blockDim.x + threadIdx.x;
    if (c >= NCOLS) return;
    float v;
    if (c < 768) v = bn[c];
    else if (c < 896) {
        int j = c - 768; v = 0.f;
#pragma unroll
        for (int s = 0; s < 6; ++s) v += bn[s * 128 + j];
    } else v = bs[c - 896];
    bvec[c] = v;
}

// ---- GEMM: P[N,1024] = bf16( (h @ Wt^T + bvec) * (norm for c<896 | 1) ) ----
__global__ void __launch_bounds__(256) k_gemm(
    const unsigned short* __restrict__ hb,
    const unsigned short* __restrict__ Wt,
    const float* __restrict__ bvec,
    const float* __restrict__ norm,
    unsigned short* __restrict__ P, int N)
{
    __shared__ char lds[(BM + BN) * BK * 2];
    char* Ab = lds;
    char* Bb = lds + BM * BK * 2;

    const int tid = threadIdx.x;
    const int wid = tid >> 6, lane = tid & 63;
    const int lrow = lane & 15, s = lane >> 4;
    const int wr = wid >> 1, wc = wid & 1;
    const int r0 = blockIdx.x * BM;
    const int c0 = blockIdx.y * BN;

    const int arow = tid >> 2;
    const int achunk = (tid & 3) ^ ((arow >> 1) & 3);
    int agrow = r0 + arow; if (agrow >= N) agrow = N - 1;
    const unsigned short* aseg = hb + (size_t)agrow * IN_F + achunk * 8;

    const int bcol0 = tid >> 2;
    const int bchunk0 = (tid & 3) ^ ((bcol0 >> 1) & 3);
    const unsigned short* bseg0 = Wt + (size_t)(c0 + bcol0) * IN_F + bchunk0 * 8;
    const int idx1 = tid + 256;
    const int bcol1 = idx1 >> 2;
    const int bchunk1 = (idx1 & 3) ^ ((bcol1 >> 1) & 3);
    const unsigned short* bseg1 = Wt + (size_t)(c0 + bcol1) * IN_F + bchunk1 * 8;

    int a_off[2], b_off[4];
#pragma unroll
    for (int m = 0; m < 2; ++m) {
        int rl = wr * 32 + m * 16 + lrow;
        a_off[m] = rl * 64 + ((s ^ ((rl >> 1) & 3)) << 4);
    }
#pragma unroll
    for (int n = 0; n < 4; ++n) {
        int cl = wc * 64 + n * 16 + lrow;
        b_off[n] = cl * 64 + ((s ^ ((cl >> 1) & 3)) << 4);
    }

    f32x4 acc[2][4] = {};

    for (int kk = 0; kk < IN_F / BK; ++kk) {
        async_load16(aseg + kk * BK, Ab + tid * 16);
        async_load16(bseg0 + kk * BK, Bb + tid * 16);
        async_load16(bseg1 + kk * BK, Bb + (tid + 256) * 16);
        __syncthreads();

        bf16x8 af[2], bfv[4];
#pragma unroll
        for (int m = 0; m < 2; ++m) af[m] = *(const bf16x8*)(Ab + a_off[m]);
#pragma unroll
        for (int n = 0; n < 4; ++n) bfv[n] = *(const bf16x8*)(Bb + b_off[n]);
#pragma unroll
        for (int m = 0; m < 2; ++m)
#pragma unroll
            for (int n = 0; n < 4; ++n)
                acc[m][n] = __builtin_amdgcn_mfma_f32_16x16x32_bf16(af[m], bfv[n], acc[m][n], 0, 0, 0);
        __syncthreads();
    }

    const bool noNorm = (c0 >= 896);   // self columns: not norm-prescaled
#pragma unroll
    for (int m = 0; m < 2; ++m) {
        const int rbase = r0 + wr * 32 + m * 16 + s * 4;
#pragma unroll
        for (int n = 0; n < 4; ++n) {
            const int cg = c0 + wc * 64 + n * 16 + lrow;
            const float bv = bvec[cg];
#pragma unroll
            for (int r = 0; r < 4; ++r) {
                const int rg = rbase + r;
                if (rg < N) {
                    float v = acc[m][n][r] + bv;
                    if (!noNorm) v *= norm[rg];
                    P[(size_t)rg * NCOLS + cg] = f2bf(v);
                }
            }
        }
    }
}

// ---- histogram over dst ----
__global__ void k_hist(const int* __restrict__ dst, int* __restrict__ counts, int E) {
    int e = blockIdx.x * blockDim.x + threadIdx.x;
    if (e < E) atomicAdd(&counts[dst[e]], 1);
}

// ---- 3-phase exclusive scan over counts[N] ----
__global__ void __launch_bounds__(256) k_scan_a(const int* __restrict__ counts,
                                                int* __restrict__ offs,
                                                int* __restrict__ bsum, int N) {
    __shared__ int sm[256];
    int tid = threadIdx.x;
    int i = blockIdx.x * 256 + tid;
    int v = (i < N) ? counts[i] : 0;
    sm[tid] = v;
    __syncthreads();
#pragma unroll
    for (int st = 1; st < 256; st <<= 1) {
        int t = (tid >= st) ? sm[tid - st] : 0;
        __syncthreads();
        sm[tid] += t;
        __syncthreads();
    }
    if (i < N) offs[i] = sm[tid] - v;        // exclusive within block
    if (tid == 255) bsum[blockIdx.x] = sm[255];
}

__global__ void __launch_bounds__(256) k_scan_b(int* __restrict__ bsum, int NB) {
    __shared__ int sm[256];
    int tid = threadIdx.x;
    int v = (tid < NB) ? bsum[tid] : 0;
    sm[tid] = v;
    __syncthreads();
#pragma unroll
    for (int st = 1; st < 256; st <<= 1) {
        int t = (tid >= st) ? sm[tid - st] : 0;
        __syncthreads();
        sm[tid] += t;
        __syncthreads();
    }
    if (tid < NB) bsum[tid] = sm[tid] - v;   // exclusive block base
}

__global__ void k_scan_c(int* __restrict__ offs, const int* __restrict__ bsum,
                         int* __restrict__ cursor, int N) {
    int i = blockIdx.x * 256 + threadIdx.x;
    if (i >= N) return;
    int o = offs[i] + bsum[blockIdx.x];
    offs[i] = o;
    cursor[i] = o;
}

// ---- scatter edges into CSR order: pedge[slot] = {src, packed degs} ----
__global__ void k_scatter(const int* __restrict__ src, const int* __restrict__ dst,
                          const float* __restrict__ degrees,
                          int* __restrict__ cursor, uint2* __restrict__ pedge, int E) {
    int e = blockIdx.x * blockDim.x + threadIdx.x;
    if (e >= E) return;
    int d = dst[e];
    int slot = atomicAdd(&cursor[d], 1);
    unsigned pk = 0;
#pragma unroll
    for (int i = 0; i < 6; ++i) {
        float df = degrees[(size_t)e * 6 + i];
        pk |= ((unsigned)df) << (4 * i);
    }
    pedge[slot] = make_uint2((unsigned)src[e], pk);
}

// ---- aggregate: one wave per dst node, fused epilogue ----
__global__ void __launch_bounds__(256) k_aggregate(
    const unsigned short* __restrict__ P,
    const int* __restrict__ row_start, const int* __restrict__ counts,
    const uint2* __restrict__ pedge,
    const float* __restrict__ norm, const float* __restrict__ W_edge,
    const float* __restrict__ bias, float* __restrict__ out, int N)
{
    int n = blockIdx.x * 4 + (threadIdx.x >> 6);
    if (n >= N) return;
    const int lane = threadIdx.x & 63;

    float2 w[6];
#pragma unroll
    for (int i = 0; i < 6; ++i) w[i] = *(const float2*)(W_edge + i * OUT_F + lane * 2);

    const int beg = row_start[n];
    const int end = beg + counts[n];
    float a0 = 0.f, a1 = 0.f;

    for (int t = beg; t < end; ++t) {
        uint2 pe = pedge[t];
        unsigned dp = pe.y;
        if (dp == 0) continue;                 // all degrees zero -> zero msg
        int sp = (int)pe.x;
        float nr = norm[sp];

        float m0 = 0.f, m1 = 0.f;
        unsigned zm = 0;
#pragma unroll
        for (int i = 0; i < 6; ++i) {
            int d = (dp >> (4 * i)) & 15;
            if (d == 0) zm |= (1u << i);
            float df = (float)d;
            m0 += df * w[i].x;
            m1 += df * w[i].y;
        }
        m0 *= nr; m1 *= nr;

        const unsigned* Ps = (const unsigned*)P + (size_t)sp * (NCOLS / 2);
        int z = __popc(zm);
        if (z <= 2) {
            unsigned u = Ps[384 + lane];       // sum-slice (norm-prescaled)
            m0 += bf_lo(u); m1 += bf_hi(u);
#pragma unroll
            for (int i = 0; i < 6; ++i) if ((zm >> i) & 1) {
                unsigned v = Ps[i * 64 + lane];
                m0 -= bf_lo(v); m1 -= bf_hi(v);
            }
        } else {
#pragma unroll
            for (int i = 0; i < 6; ++i) if (!((zm >> i) & 1)) {
                unsigned v = Ps[i * 64 + lane];
                m0 += bf_lo(v); m1 += bf_hi(v);
            }
        }
        a0 += m0; a1 += m1;
    }

    // fused epilogue: relu(accum*norm[n] + self + bias)
    const unsigned* Pn = (const unsigned*)P + (size_t)n * (NCOLS / 2);
    unsigned us = Pn[448 + lane];              // self cols (unscaled, b_self folded in)
    float nd = norm[n];
    float2 bv = *(const float2*)(bias + lane * 2);
    float2 o;
    o.x = fmaxf(a0 * nd + bf_lo(us) + bv.x, 0.f);
    o.y = fmaxf(a1 * nd + bf_hi(us) + bv.y, 0.f);
    *(float2*)(out + (size_t)n * OUT_F + lane * 2) = o;
}

extern "C" void kernel_launch(void* const* d_in, const int* in_sizes, int n_in,
                              void* d_out, int out_size, void* d_ws, size_t ws_size,
                              hipStream_t stream)
{
    const float* h       = (const float*)d_in[0];
    const float* degrees = (const float*)d_in[1];
    const float* norm    = (const float*)d_in[2];
    const int*   src     = (const int*)d_in[3];
    const int*   dst     = (const int*)d_in[4];
    const float* W_self  = (const float*)d_in[5];
    const float* b_self  = (const float*)d_in[6];
    const float* W_node  = (const float*)d_in[7];
    const float* b_node  = (const float*)d_in[8];
    const float* W_edge  = (const float*)d_in[9];
    const float* bias    = (const float*)d_in[10];
    float* out = (float*)d_out;

    const int N = in_sizes[2];   // norm [N,1]
    const int E = in_sizes[3];   // src [E]
    const int NB = (N + 255) / 256;

    // ---- workspace layout (~135.5 MB) ----
    char* ws = (char*)d_ws;
    size_t off = 0;
    auto alloc = [&](size_t sz) { size_t o = off; off = (off + sz + 255) & ~(size_t)255; return o; };
    unsigned short* P      = (unsigned short*)(ws + alloc((size_t)N * NCOLS * 2)); // 102.4 MB
    unsigned short* hb     = (unsigned short*)(ws + alloc((size_t)N * IN_F * 2));  // 25.6 MB
    unsigned short* Wt     = (unsigned short*)(ws + alloc((size_t)NCOLS * IN_F * 2));
    float*          bvec   = (float*)(ws + alloc(NCOLS * 4));
    int*            counts = (int*)(ws + alloc((size_t)N * 4));
    int*            offs   = (int*)(ws + alloc((size_t)N * 4));
    int*            cursor = (int*)(ws + alloc((size_t)N * 4));
    int*            bsum   = (int*)(ws + alloc((size_t)NB * 4));
    uint2*          pedge  = (uint2*)(ws + alloc((size_t)E * 8));                  // 6.4 MB

    hipMemsetAsync(counts, 0, (size_t)N * 4, stream);

    int t8 = N * (IN_F / 8);
    k_conv_h<<<(t8 + 255) / 256, 256, 0, stream>>>(h, hb, t8);

    int tw = IN_F * NCOLS;
    k_conv_w<<<(tw + 255) / 256, 256, 0, stream>>>(W_node, W_self, Wt, tw);
    k_conv_b<<<(NCOLS + 255) / 256, 256, 0, stream>>>(b_node, b_self, bvec);

    dim3 gg((N + BM - 1) / BM, NCOLS / BN);
    k_gemm<<<gg, 256, 0, stream>>>(hb, Wt, bvec, norm, P, N);

    k_hist<<<(E + 255) / 256, 256, 0, stream>>>(dst, counts, E);
    k_scan_a<<<NB, 256, 0, stream>>>(counts, offs, bsum, N);
    k_scan_b<<<1, 256, 0, stream>>>(bsum, NB);
    k_scan_c<<<NB, 256, 0, stream>>>(offs, bsum, cursor, N);
    k_scatter<<<(E + 255) / 256, 256, 0, stream>>>(src, dst, degrees, cursor, pedge, E);

    k_aggregate<<<(N + 3) / 4, 256, 0, stream>>>(P, offs, counts, pedge, norm, W_edge, bias, out, N);
}

// Round 3
// 266.144 us; speedup vs baseline: 2.9921x; 1.5001x over previous
//
#include <hip/hip_runtime.h>
#include <stdint.h>

#define IN_F 256
#define OUT_F 128
#define NCOLS 1024   // 768 node-msg cols + 128 sum-slice + 128 self
#define BM 64
#define BN 128
#define BK 32

using bf16x8 = __attribute__((ext_vector_type(8))) __bf16;
using f32x4  = __attribute__((ext_vector_type(4))) float;

static __device__ __forceinline__ unsigned short f2bf(float f) {
    unsigned u = __float_as_uint(f);
    u = u + 0x7fffu + ((u >> 16) & 1u);   // RNE
    return (unsigned short)(u >> 16);
}
static __device__ __forceinline__ float bf_lo(unsigned u) { return __uint_as_float(u << 16); }
static __device__ __forceinline__ float bf_hi(unsigned u) { return __uint_as_float(u & 0xffff0000u); }

static __device__ __forceinline__ void async_load16(const void* g, void* l) {
    __builtin_amdgcn_global_load_lds(
        (__attribute__((address_space(1))) void*)g,
        (__attribute__((address_space(3))) void*)l,
        16, 0, 0);
}

// ---- h (f32) -> bf16 ----
__global__ void k_conv_h(const float* __restrict__ h, unsigned short* __restrict__ hb, int total8) {
    int i = blockIdx.x * blockDim.x + threadIdx.x;
    if (i >= total8) return;
    const float4* src = ((const float4*)h) + (size_t)i * 2;
    float4 a = src[0], b = src[1];
    union { unsigned short us[8]; uint4 v; } u;
    u.us[0] = f2bf(a.x); u.us[1] = f2bf(a.y); u.us[2] = f2bf(a.z); u.us[3] = f2bf(a.w);
    u.us[4] = f2bf(b.x); u.us[5] = f2bf(b.y); u.us[6] = f2bf(b.z); u.us[7] = f2bf(b.w);
    ((uint4*)hb)[i] = u.v;
}

// ---- Wt[1024][256] = [W_node | sum(W_node slices) | W_self]^T, bf16 ----
__global__ void k_conv_w(const float* __restrict__ Wn, const float* __restrict__ Ws,
                         unsigned short* __restrict__ Wt, int total) {
    int i = blockIdx.x * blockDim.x + threadIdx.x;   // i = k*1024 + c
    if (i >= total) return;
    int k = i >> 10, c = i & 1023;
    float v;
    if (c < 768) {
        v = Wn[(size_t)k * 768 + c];
    } else if (c < 896) {
        int j = c - 768; v = 0.f;
#pragma unroll
        for (int s = 0; s < 6; ++s) v += Wn[(size_t)k * 768 + s * 128 + j];
    } else {
        v = Ws[(size_t)k * 128 + (c - 896)];
    }
    Wt[(size_t)c * IN_F + k] = f2bf(v);
}

// ---- combined bias vector bvec[1024] ----
__global__ void k_conv_b(const float* __restrict__ bn, const float* __restrict__ bs,
                         float* __restrict__ bvec) {
    int c = blockIdx.x * blockDim.x + threadIdx.x;
    if (c >= NCOLS) return;
    float v;
    if (c < 768) v = bn[c];
    else if (c < 896) {
        int j = c - 768; v = 0.f;
#pragma unroll
        for (int s = 0; s < 6; ++s) v += bn[s * 128 + j];
    } else v = bs[c - 896];
    bvec[c] = v;
}

// ---- GEMM: P[N,1024] = bf16( (h @ Wt^T + bvec) * (norm for c<896 | 1) ) ----
__global__ void __launch_bounds__(256) k_gemm(
    const unsigned short* __restrict__ hb,
    const unsigned short* __restrict__ Wt,
    const float* __restrict__ bvec,
    const float* __restrict__ norm,
    unsigned short* __restrict__ P, int N)
{
    __shared__ char lds[(BM + BN) * BK * 2];
    char* Ab = lds;
    char* Bb = lds + BM * BK * 2;

    const int tid = threadIdx.x;
    const int wid = tid >> 6, lane = tid & 63;
    const int lrow = lane & 15, s = lane >> 4;
    const int wr = wid >> 1, wc = wid & 1;
    const int r0 = blockIdx.y * BM;      // row block on slow axis
    const int c0 = blockIdx.x * BN;      // col block on fast axis -> A-tile reuse in L2

    const int arow = tid >> 2;
    const int achunk = (tid & 3) ^ ((arow >> 1) & 3);
    int agrow = r0 + arow; if (agrow >= N) agrow = N - 1;
    const unsigned short* aseg = hb + (size_t)agrow * IN_F + achunk * 8;

    const int bcol0 = tid >> 2;
    const int bchunk0 = (tid & 3) ^ ((bcol0 >> 1) & 3);
    const unsigned short* bseg0 = Wt + (size_t)(c0 + bcol0) * IN_F + bchunk0 * 8;
    const int idx1 = tid + 256;
    const int bcol1 = idx1 >> 2;
    const int bchunk1 = (idx1 & 3) ^ ((bcol1 >> 1) & 3);
    const unsigned short* bseg1 = Wt + (size_t)(c0 + bcol1) * IN_F + bchunk1 * 8;

    int a_off[2], b_off[4];
#pragma unroll
    for (int m = 0; m < 2; ++m) {
        int rl = wr * 32 + m * 16 + lrow;
        a_off[m] = rl * 64 + ((s ^ ((rl >> 1) & 3)) << 4);
    }
#pragma unroll
    for (int n = 0; n < 4; ++n) {
        int cl = wc * 64 + n * 16 + lrow;
        b_off[n] = cl * 64 + ((s ^ ((cl >> 1) & 3)) << 4);
    }

    f32x4 acc[2][4] = {};

    for (int kk = 0; kk < IN_F / BK; ++kk) {
        async_load16(aseg + kk * BK, Ab + tid * 16);
        async_load16(bseg0 + kk * BK, Bb + tid * 16);
        async_load16(bseg1 + kk * BK, Bb + (tid + 256) * 16);
        __syncthreads();

        bf16x8 af[2], bfv[4];
#pragma unroll
        for (int m = 0; m < 2; ++m) af[m] = *(const bf16x8*)(Ab + a_off[m]);
#pragma unroll
        for (int n = 0; n < 4; ++n) bfv[n] = *(const bf16x8*)(Bb + b_off[n]);
#pragma unroll
        for (int m = 0; m < 2; ++m)
#pragma unroll
            for (int n = 0; n < 4; ++n)
                acc[m][n] = __builtin_amdgcn_mfma_f32_16x16x32_bf16(af[m], bfv[n], acc[m][n], 0, 0, 0);
        __syncthreads();
    }

    const bool noNorm = (c0 >= 896);
#pragma unroll
    for (int m = 0; m < 2; ++m) {
        const int rbase = r0 + wr * 32 + m * 16 + s * 4;
#pragma unroll
        for (int n = 0; n < 4; ++n) {
            const int cg = c0 + wc * 64 + n * 16 + lrow;
            const float bv = bvec[cg];
#pragma unroll
            for (int r = 0; r < 4; ++r) {
                const int rg = rbase + r;
                if (rg < N) {
                    float v = acc[m][n][r] + bv;
                    if (!noNorm) v *= norm[rg];
                    P[(size_t)rg * NCOLS + cg] = f2bf(v);
                }
            }
        }
    }
}

// ---- histogram over dst ----
__global__ void k_hist(const int* __restrict__ dst, int* __restrict__ counts, int E) {
    int e = blockIdx.x * blockDim.x + threadIdx.x;
    if (e < E) atomicAdd(&counts[dst[e]], 1);
}

// ---- 3-phase exclusive scan over counts[N] ----
__global__ void __launch_bounds__(256) k_scan_a(const int* __restrict__ counts,
                                                int* __restrict__ offs,
                                                int* __restrict__ bsum, int N) {
    __shared__ int sm[256];
    int tid = threadIdx.x;
    int i = blockIdx.x * 256 + tid;
    int v = (i < N) ? counts[i] : 0;
    sm[tid] = v;
    __syncthreads();
#pragma unroll
    for (int st = 1; st < 256; st <<= 1) {
        int t = (tid >= st) ? sm[tid - st] : 0;
        __syncthreads();
        sm[tid] += t;
        __syncthreads();
    }
    if (i < N) offs[i] = sm[tid] - v;
    if (tid == 255) bsum[blockIdx.x] = sm[255];
}

__global__ void __launch_bounds__(256) k_scan_b(int* __restrict__ bsum, int NB) {
    __shared__ int sm[256];
    int tid = threadIdx.x;
    int v = (tid < NB) ? bsum[tid] : 0;
    sm[tid] = v;
    __syncthreads();
#pragma unroll
    for (int st = 1; st < 256; st <<= 1) {
        int t = (tid >= st) ? sm[tid - st] : 0;
        __syncthreads();
        sm[tid] += t;
        __syncthreads();
    }
    if (tid < NB) bsum[tid] = sm[tid] - v;
}

__global__ void k_scan_c(int* __restrict__ offs, const int* __restrict__ bsum,
                         int* __restrict__ cursor, int N) {
    int i = blockIdx.x * 256 + threadIdx.x;
    if (i >= N) return;
    int o = offs[i] + bsum[blockIdx.x];
    offs[i] = o;
    cursor[i] = o;
}

// ---- scatter edges into CSR order: pedge[slot] = {src, packed degs} ----
__global__ void k_scatter(const int* __restrict__ src, const int* __restrict__ dst,
                          const float* __restrict__ degrees,
                          int* __restrict__ cursor, uint2* __restrict__ pedge, int E) {
    int e = blockIdx.x * blockDim.x + threadIdx.x;
    if (e >= E) return;
    int d = dst[e];
    int slot = atomicAdd(&cursor[d], 1);
    unsigned pk = 0;
#pragma unroll
    for (int i = 0; i < 6; ++i) {
        float df = degrees[(size_t)e * 6 + i];
        pk |= ((unsigned)df) << (4 * i);
    }
    pedge[slot] = make_uint2((unsigned)src[e], pk);
}

// ---- aggregate v2: lane-parallel metadata + LDS gather worklist ----
__global__ void __launch_bounds__(256) k_aggregate(
    const unsigned short* __restrict__ P,
    const int* __restrict__ row_start, const int* __restrict__ counts,
    const uint2* __restrict__ pedge,
    const float* __restrict__ norm, const float* __restrict__ W_edge,
    const float* __restrict__ bias, float* __restrict__ out, int N)
{
    __shared__ unsigned EL[4][192];
    const int wid = threadIdx.x >> 6;
    const int n = blockIdx.x * 4 + wid;
    if (n >= N) return;
    const int lane = threadIdx.x & 63;
    unsigned* el = EL[wid];

    float2 w[6];
#pragma unroll
    for (int i = 0; i < 6; ++i) w[i] = *(const float2*)(W_edge + i * OUT_F + lane * 2);

    const int beg = row_start[n];
    const int end = beg + counts[n];
    const unsigned* __restrict__ Pd = (const unsigned*)P;

    float Swd[6] = {0.f, 0.f, 0.f, 0.f, 0.f, 0.f};   // per-lane partial of sum(nr * deg_i)
    float g0 = 0.f, g1 = 0.f;                        // gather accumulator (2 cols per lane)

    for (int p0 = beg; p0 < end; p0 += 64) {
        // ---- phase A: lane t handles edge p0+t ----
        const int t = p0 + lane;
        const bool valid = t < end;
        uint2 pe = valid ? pedge[t] : make_uint2(0u, 0u);
        const unsigned dp = pe.y;                    // dp==0 also for invalid lanes
        const float nr = (dp != 0u) ? norm[pe.x] : 0.f;

        unsigned zm = 0;
#pragma unroll
        for (int i = 0; i < 6; ++i) {
            int d = (dp >> (4 * i)) & 15;
            if (d == 0) zm |= (1u << i);
            Swd[i] += nr * (float)d;
        }
        const int z = __popc(zm);
        const int ne = (dp == 0u) ? 0 : ((z <= 2) ? (1 + z) : (6 - z));

        // inclusive wave prefix-sum of ne
        int x = ne;
#pragma unroll
        for (int st = 1; st < 64; st <<= 1) {
            int v = __shfl_up(x, st);
            if (lane >= st) x += v;
        }
        const int excl = x - ne;
        const int total = __shfl(x, 63);

        if (ne) {
            const unsigned base = pe.x * 512u;       // dword index of P row
            int wp = excl;
            if (z <= 2) {
                el[wp++] = base + 384u;              // + sum-slice
#pragma unroll
                for (int i = 0; i < 6; ++i)
                    if ((zm >> i) & 1u) el[wp++] = (base + i * 64u) | 0x80000000u;  // - zero slices
            } else {
#pragma unroll
                for (int i = 0; i < 6; ++i)
                    if (!((zm >> i) & 1u)) el[wp++] = base + i * 64u;               // + nonzero slices
            }
        }
        asm volatile("s_waitcnt lgkmcnt(0)" ::: "memory");

        // ---- phase B: uniform gather loop, 4-deep MLP ----
        int j = 0;
        for (; j + 4 <= total; j += 4) {
            unsigned e0 = el[j], e1 = el[j + 1], e2 = el[j + 2], e3 = el[j + 3];
            unsigned u0 = Pd[(e0 & 0x7fffffffu) + lane];
            unsigned u1 = Pd[(e1 & 0x7fffffffu) + lane];
            unsigned u2 = Pd[(e2 & 0x7fffffffu) + lane];
            unsigned u3 = Pd[(e3 & 0x7fffffffu) + lane];
            float s0 = __uint_as_float(0x3f800000u | (e0 & 0x80000000u));
            float s1 = __uint_as_float(0x3f800000u | (e1 & 0x80000000u));
            float s2 = __uint_as_float(0x3f800000u | (e2 & 0x80000000u));
            float s3 = __uint_as_float(0x3f800000u | (e3 & 0x80000000u));
            g0 += s0 * bf_lo(u0); g1 += s0 * bf_hi(u0);
            g0 += s1 * bf_lo(u1); g1 += s1 * bf_hi(u1);
            g0 += s2 * bf_lo(u2); g1 += s2 * bf_hi(u2);
            g0 += s3 * bf_lo(u3); g1 += s3 * bf_hi(u3);
        }
        for (; j < total; ++j) {
            unsigned e0 = el[j];
            unsigned u0 = Pd[(e0 & 0x7fffffffu) + lane];
            float s0 = __uint_as_float(0x3f800000u | (e0 & 0x80000000u));
            g0 += s0 * bf_lo(u0); g1 += s0 * bf_hi(u0);
        }
    }

    // ---- reduce Swd across the wave, fold base term ----
    float b0 = 0.f, b1 = 0.f;
#pragma unroll
    for (int i = 0; i < 6; ++i) {
        float v = Swd[i];
#pragma unroll
        for (int st = 1; st < 64; st <<= 1) v += __shfl_xor(v, st);
        b0 += v * w[i].x;
        b1 += v * w[i].y;
    }

    // ---- fused epilogue: relu(accum*norm[n] + self + bias) ----
    const unsigned us = Pd[(size_t)n * 512 + 448 + lane];
    const float nd = norm[n];
    const float2 bv = *(const float2*)(bias + lane * 2);
    float2 o;
    o.x = fmaxf((g0 + b0) * nd + bf_lo(us) + bv.x, 0.f);
    o.y = fmaxf((g1 + b1) * nd + bf_hi(us) + bv.y, 0.f);
    *(float2*)(out + (size_t)n * OUT_F + lane * 2) = o;
}

extern "C" void kernel_launch(void* const* d_in, const int* in_sizes, int n_in,
                              void* d_out, int out_size, void* d_ws, size_t ws_size,
                              hipStream_t stream)
{
    const float* h       = (const float*)d_in[0];
    const float* degrees = (const float*)d_in[1];
    const float* norm    = (const float*)d_in[2];
    const int*   src     = (const int*)d_in[3];
    const int*   dst     = (const int*)d_in[4];
    const float* W_self  = (const float*)d_in[5];
    const float* b_self  = (const float*)d_in[6];
    const float* W_node  = (const float*)d_in[7];
    const float* b_node  = (const float*)d_in[8];
    const float* W_edge  = (const float*)d_in[9];
    const float* bias    = (const float*)d_in[10];
    float* out = (float*)d_out;

    const int N = in_sizes[2];   // norm [N,1]
    const int E = in_sizes[3];   // src [E]
    const int NB = (N + 255) / 256;

    char* ws = (char*)d_ws;
    size_t off = 0;
    auto alloc = [&](size_t sz) { size_t o = off; off = (off + sz + 255) & ~(size_t)255; return o; };
    unsigned short* P      = (unsigned short*)(ws + alloc((size_t)N * NCOLS * 2)); // 102.4 MB
    unsigned short* hb     = (unsigned short*)(ws + alloc((size_t)N * IN_F * 2));  // 25.6 MB
    unsigned short* Wt     = (unsigned short*)(ws + alloc((size_t)NCOLS * IN_F * 2));
    float*          bvec   = (float*)(ws + alloc(NCOLS * 4));
    int*            counts = (int*)(ws + alloc((size_t)N * 4));
    int*            offs   = (int*)(ws + alloc((size_t)N * 4));
    int*            cursor = (int*)(ws + alloc((size_t)N * 4));
    int*            bsum   = (int*)(ws + alloc((size_t)NB * 4));
    uint2*          pedge  = (uint2*)(ws + alloc((size_t)E * 8));                  // 6.4 MB

    hipMemsetAsync(counts, 0, (size_t)N * 4, stream);

    int t8 = N * (IN_F / 8);
    k_conv_h<<<(t8 + 255) / 256, 256, 0, stream>>>(h, hb, t8);

    int tw = IN_F * NCOLS;
    k_conv_w<<<(tw + 255) / 256, 256, 0, stream>>>(W_node, W_self, Wt, tw);
    k_conv_b<<<(NCOLS + 255) / 256, 256, 0, stream>>>(b_node, b_self, bvec);

    dim3 gg(NCOLS / BN, (N + BM - 1) / BM);   // col block fast -> A-tile L2 reuse
    k_gemm<<<gg, 256, 0, stream>>>(hb, Wt, bvec, norm, P, N);

    k_hist<<<(E + 255) / 256, 256, 0, stream>>>(dst, counts, E);
    k_scan_a<<<NB, 256, 0, stream>>>(counts, offs, bsum, N);
    k_scan_b<<<1, 256, 0, stream>>>(bsum, NB);
    k_scan_c<<<NB, 256, 0, stream>>>(offs, bsum, cursor, N);
    k_scatter<<<(E + 255) / 256, 256, 0, stream>>>(src, dst, degrees, cursor, pedge, E);

    k_aggregate<<<(N + 3) / 4, 256, 0, stream>>>(P, offs, counts, pedge, norm, W_edge, bias, out, N);
}